// Round 15
// baseline (1022.879 us; speedup 1.0000x reference)
//
#include <hip/hip_runtime.h>
#include <hip/hip_bf16.h>

#define NLAYER 4
#define NHEAD 8
#define CEMB 512
#define HS 64
#define VOCAB_N 32000
#define SEQT 2048
#define BATCH_N 2
#define MROWS (BATCH_N * SEQT)   /* 4096 */
#define WIN 64
#define NGLOB 16
#define NRAND 16
#define QB 16
#define VTW 104
#define PSW 104

typedef __attribute__((ext_vector_type(8))) __bf16 bf16x8;
typedef __attribute__((ext_vector_type(4))) float f32x4;
typedef __attribute__((ext_vector_type(8))) unsigned short u16x8;

__device__ __forceinline__ unsigned short f2bf(float f) {
    unsigned u = __float_as_uint(f);
    u += 0x7fffu + ((u >> 16) & 1u);      // RNE
    return (unsigned short)(u >> 16);
}
__device__ __forceinline__ float bf2f(unsigned short v) {
    return __uint_as_float((unsigned)v << 16);
}

// async global->LDS, 16B per lane
__device__ __forceinline__ void stage16(const unsigned short* g, unsigned short* l) {
    __builtin_amdgcn_global_load_lds(
        (const __attribute__((address_space(1))) void*)g,
        (__attribute__((address_space(3))) void*)l, 16, 0, 0);
}

// ---------------------------------------------------------------- unified weight transpose
__global__ __launch_bounds__(256) void transpose_all_kernel(
    const float* __restrict__ Wq, const float* __restrict__ Wk,
    const float* __restrict__ Wv, const float* __restrict__ Wproj,
    const float* __restrict__ W1, const float* __restrict__ W2,
    const float* __restrict__ Wout,
    unsigned short* __restrict__ wqkvT, unsigned short* __restrict__ wprojT,
    unsigned short* __restrict__ w1T, unsigned short* __restrict__ w2T,
    unsigned short* __restrict__ woutT)
{
    __shared__ float tle[64][65];
    const int bid = blockIdx.x;
    const float* src; unsigned short* dst; int Ks, Ns, k0, n0;
    if (bid < 768) {
        const int tile = bid & 7, rest = bid >> 3;
        const int l = rest / 24, r2 = rest % 24;
        const int sel = r2 >> 3, h = r2 & 7;
        const float* W = (sel == 0) ? Wq : (sel == 1) ? Wk : Wv;
        src = W + (size_t)(l * 8 + h) * 512 * 64;
        dst = wqkvT + ((size_t)l * 1536 + sel * 512 + h * 64) * 512;
        Ks = 512; Ns = 64; k0 = tile * 64; n0 = 0;
    } else if (bid < 1024) {
        const int idx = bid - 768, l = idx >> 6, t6 = idx & 63;
        src = Wproj + (size_t)l * 512 * 512;
        dst = wprojT + (size_t)l * 512 * 512;
        Ks = 512; Ns = 512; k0 = (t6 >> 3) * 64; n0 = (t6 & 7) * 64;
    } else if (bid < 2048) {
        const int idx = bid - 1024, l = idx >> 8, t8 = idx & 255;
        src = W1 + (size_t)l * 512 * 2048;
        dst = w1T + (size_t)l * 2048 * 512;
        Ks = 512; Ns = 2048; k0 = (t8 >> 5) * 64; n0 = (t8 & 31) * 64;
    } else if (bid < 3072) {
        const int idx = bid - 2048, l = idx >> 8, t8 = idx & 255;
        src = W2 + (size_t)l * 2048 * 512;
        dst = w2T + (size_t)l * 512 * 2048;
        Ks = 2048; Ns = 512; k0 = (t8 >> 3) * 64; n0 = (t8 & 7) * 64;
    } else {
        const int idx = bid - 3072;
        src = Wout; dst = woutT;
        Ks = 512; Ns = 32000; k0 = (idx / 500) * 64; n0 = (idx % 500) * 64;
    }
    const int tid = threadIdx.x;
    #pragma unroll
    for (int i = 0; i < 16; ++i) {
        const int idx = tid + i * 256;
        const int r = idx >> 6, c = idx & 63;
        tle[r][c] = src[(size_t)(k0 + r) * Ns + n0 + c];
    }
    __syncthreads();
    #pragma unroll
    for (int i = 0; i < 16; ++i) {
        const int idx = tid + i * 256;
        const int c = idx >> 6, r = idx & 63;
        dst[(size_t)(n0 + c) * Ks + k0 + r] = f2bf(tle[r][c]);
    }
}

// ---------------------------------------------------------------- embedding
__global__ __launch_bounds__(256) void embed_kernel(
    const float* __restrict__ tok_emb, const float* __restrict__ pos_emb,
    const int* __restrict__ toks, float* __restrict__ x)
{
    int i = blockIdx.x * 256 + threadIdx.x;
    int m = i >> 7;
    int c = (i & 127) << 2;
    int tok = toks[m];
    const float4 a = *(const float4*)&tok_emb[(size_t)tok * CEMB + c];
    const float4 p = *(const float4*)&pos_emb[(size_t)(m & (SEQT - 1)) * CEMB + c];
    float4 o;
    o.x = a.x + p.x; o.y = a.y + p.y; o.z = a.z + p.z; o.w = a.w + p.w;
    *(float4*)&x[(size_t)m * CEMB + c] = o;
}

// ---------------------------------------------------------------- layernorm
__global__ __launch_bounds__(256) void ln_kernel(
    const float* __restrict__ x, const float* __restrict__ g,
    const float* __restrict__ b, unsigned short* __restrict__ out)
{
    const int wave = threadIdx.x >> 6, lane = threadIdx.x & 63;
    const int m = blockIdx.x * 4 + wave;
    const float* row = x + (size_t)m * CEMB;
    const float4 v0 = *(const float4*)&row[lane * 8];
    const float4 v1 = *(const float4*)&row[lane * 8 + 4];
    float s  = v0.x + v0.y + v0.z + v0.w + v1.x + v1.y + v1.z + v1.w;
    float s2 = v0.x*v0.x + v0.y*v0.y + v0.z*v0.z + v0.w*v0.w
             + v1.x*v1.x + v1.y*v1.y + v1.z*v1.z + v1.w*v1.w;
    #pragma unroll
    for (int off = 32; off > 0; off >>= 1) {
        s  += __shfl_xor(s, off);
        s2 += __shfl_xor(s2, off);
    }
    const float mu  = s * (1.f / CEMB);
    const float var = s2 * (1.f / CEMB) - mu * mu;
    const float rs  = rsqrtf(var + 1e-5f);
    const float vals[8] = {v0.x, v0.y, v0.z, v0.w, v1.x, v1.y, v1.z, v1.w};
    u16x8 o;
    #pragma unroll
    for (int j = 0; j < 8; ++j)
        o[j] = f2bf((vals[j] - mu) * rs * g[lane * 8 + j] + b[lane * 8 + j]);
    *(u16x8*)&out[(size_t)m * CEMB + lane * 8] = o;
}

// ---------------------------------------------------------------- MFMA GEMM (r8 triple-buffer counted vmcnt + T2 swizzle)
// MODE 0: bf16 out, no bias | 1: f32 out +bias +resid | 2: bf16 out +bias relu
template<int MODE, int NF>
__global__ __launch_bounds__(256) void gemm_kernel(
    const unsigned short* __restrict__ A, const unsigned short* __restrict__ Bt,
    const float* __restrict__ bias, const float* resid, void* outp,
    int M, int N, int K)
{
    __shared__ unsigned short sa[3][128 * 32];
    __shared__ unsigned short sb[3][NF * 32 * 32];
    const int tid = threadIdx.x;
    const int lane = tid & 63;
    const int wave = tid >> 6;
    const int wr = wave >> 1, wc = wave & 1;
    const int m0 = blockIdx.y * 128;
    const int n0 = blockIdx.x * (NF * 32);

    const int c0a = (wave * 2) * 64 + lane;
    const int c1a = (wave * 2 + 1) * 64 + lane;
    const int r0 = c0a >> 2, kk0 = (((c0a & 3) ^ ((r0 >> 1) & 3)) * 8);
    const int r1 = c1a >> 2, kk1 = (((c1a & 3) ^ ((r1 >> 1) & 3)) * 8);
    const unsigned short* ga0 = A + (size_t)(m0 + r0) * K + kk0;
    const unsigned short* ga1 = A + (size_t)(m0 + r1) * K + kk1;
    const int o0 = (wave * 2) * 512;
    const int o1 = (wave * 2 + 1) * 512;
    const int cb0 = (NF == 4) ? c0a : wave * 64 + lane;
    const int cb1 = c1a;
    const int rb0 = cb0 >> 2, kb0 = (((cb0 & 3) ^ ((rb0 >> 1) & 3)) * 8);
    const int rb1 = cb1 >> 2, kb1 = (((cb1 & 3) ^ ((rb1 >> 1) & 3)) * 8);
    const unsigned short* gb0 = Bt + (size_t)(n0 + rb0) * K + kb0;
    const unsigned short* gb1 = Bt + (size_t)(n0 + rb1) * K + kb1;
    const int ob0 = (NF == 4) ? o0 : wave * 512;
    const int ob1 = o1;

    f32x4 acc[4][NF] = {};
    const int lq = lane >> 4;
    const int fr = lane & 15;

    auto STAGE = [&](int tile, int buf) {
        const int kk = tile << 5;
        stage16(ga0 + kk, &sa[buf][o0]);
        stage16(ga1 + kk, &sa[buf][o1]);
        stage16(gb0 + kk, &sb[buf][ob0]);
        if constexpr (NF == 4) stage16(gb1 + kk, &sb[buf][ob1]);
    };

    const int nt = K >> 5;
    STAGE(0, 0);
    STAGE(1, 1);

    int cur = 0;
    for (int t = 0; t < nt; ++t) {
        if (t + 1 < nt) {
            if constexpr (NF == 2) asm volatile("s_waitcnt vmcnt(3)" ::: "memory");
            else                   asm volatile("s_waitcnt vmcnt(4)" ::: "memory");
        } else {
            asm volatile("s_waitcnt vmcnt(0)" ::: "memory");
        }
        __builtin_amdgcn_s_barrier();
        __builtin_amdgcn_sched_barrier(0);

        if (t + 2 < nt) {
            int b2 = cur + 2; if (b2 >= 3) b2 -= 3;
            STAGE(t + 2, b2);
        }

        bf16x8 af[4], bfr[NF];
        #pragma unroll
        for (int i = 0; i < 4; ++i) {
            const int Ra = wr * 64 + i * 16 + fr;
            af[i] = *reinterpret_cast<const bf16x8*>(
                &sa[cur][Ra * 32 + (((lq ^ ((Ra >> 1) & 3))) << 3)]);
        }
        #pragma unroll
        for (int i = 0; i < NF; ++i) {
            const int Rb = wc * (NF * 16) + i * 16 + fr;
            bfr[i] = *reinterpret_cast<const bf16x8*>(
                &sb[cur][Rb * 32 + (((lq ^ ((Rb >> 1) & 3))) << 3)]);
        }
        #pragma unroll
        for (int mi = 0; mi < 4; ++mi)
            #pragma unroll
            for (int ni = 0; ni < NF; ++ni)
                acc[mi][ni] = __builtin_amdgcn_mfma_f32_16x16x32_bf16(af[mi], bfr[ni], acc[mi][ni], 0, 0, 0);

        cur = (cur == 2) ? 0 : cur + 1;
    }

    #pragma unroll
    for (int mi = 0; mi < 4; ++mi) {
        #pragma unroll
        for (int ni = 0; ni < NF; ++ni) {
            const int gc = n0 + wc * (NF * 16) + ni * 16 + fr;
            const float bv = (MODE != 0) ? bias[gc] : 0.f;
            #pragma unroll
            for (int r = 0; r < 4; ++r) {
                const int gr = m0 + wr * 64 + mi * 16 + lq * 4 + r;
                float v = acc[mi][ni][r] + bv;
                if (MODE == 1) v += resid[(size_t)gr * N + gc];
                if (MODE == 2) v = fmaxf(v, 0.f);
                if (MODE == 0 || MODE == 2) {
                    ((unsigned short*)outp)[(size_t)gr * N + gc] = f2bf(v);
                } else {
                    ((float*)outp)[(size_t)gr * N + gc] = v;
                }
            }
        }
    }
}

// ---------------------------------------------------------------- logits GEMM v2b: 128x256 tile, BK=32, 512 thr (8 waves 2Mx4N)
// Staging (FIXED coverage): every thread stages 2 B-chunks (1024 total) +
// 1 A-chunk (512 total) per tile -> 3 stage16/thread, uniform across waves.
// 2 LDS buffers; counted vmcnt(3) at top (tile t landed, t+1 in flight,
// never 0 mid-loop); phase-split K-step with setprio; STAGE(t+2) into the
// just-freed buffer after the end barrier. T2 read/source swizzle; XCD
// column-major block swizzle (B-panel L2-resident).
__global__ __launch_bounds__(512) void gemm_logits_kernel(
    const unsigned short* __restrict__ A, const unsigned short* __restrict__ Bt,
    const float* __restrict__ bias, float* __restrict__ outp,
    int M, int N, int K)
{
    __shared__ unsigned short sa[2][128 * 32];   // 8 KB each  (512 chunks)
    __shared__ unsigned short sb[2][256 * 32];   // 16 KB each (1024 chunks)
    const int tid = threadIdx.x;
    const int lane = tid & 63;
    const int wave = tid >> 6;
    const int wr = wave >> 2, wc = wave & 3;
    const int lq = lane >> 4, fr = lane & 15;

    const int flat = blockIdx.y * gridDim.x + blockIdx.x;   // 0..3999 (x=125 fast)
    const int q = (gridDim.x * gridDim.y) >> 3;             // 500
    const int nl = (flat & 7) * q + (flat >> 3);
    const int by = nl & 31;          // M-block (32)
    const int bx = nl >> 5;          // N-block (125)
    const int m0 = by * 128;
    const int n0 = bx * 256;

    // B staging: chunks tid and tid+512 (1024 chunks = 256 rows x 4)
    const int cB0 = tid,      rB0 = cB0 >> 2, kB0 = (((cB0 & 3) ^ ((rB0 >> 1) & 3)) * 8);
    const int cB1 = tid + 512, rB1 = cB1 >> 2, kB1 = (((cB1 & 3) ^ ((rB1 >> 1) & 3)) * 8);
    const unsigned short* gb0 = Bt + (size_t)(n0 + rB0) * K + kB0;
    const unsigned short* gb1 = Bt + (size_t)(n0 + rB1) * K + kB1;
    // A staging: chunk tid (512 chunks = 128 rows x 4)
    const int cA = tid, rA = cA >> 2, kA = (((cA & 3) ^ ((rA >> 1) & 3)) * 8);
    const unsigned short* ga = A + (size_t)(m0 + rA) * K + kA;

    // LDS dests: chunk c at u16 offset c*8; per-wave uniform base + lane*16B
    unsigned short* const sb0d[2] = { &sb[0][(size_t)wave * 512], &sb[1][(size_t)wave * 512] };
    unsigned short* const sb1d[2] = { &sb[0][(size_t)wave * 512 + 4096], &sb[1][(size_t)wave * 512 + 4096] };
    unsigned short* const sad[2]  = { &sa[0][(size_t)wave * 512], &sa[1][(size_t)wave * 512] };

    f32x4 acc[4][4] = {};

    auto STAGE = [&](int t, int buf) {
        const int kk = t << 5;
        stage16(gb0 + kk, sb0d[buf]);
        stage16(gb1 + kk, sb1d[buf]);
        stage16(ga + kk,  sad[buf]);
    };

    const int nt = K >> 5;           // 16
    STAGE(0, 0);
    STAGE(1, 1);

    int cur = 0;
    for (int t = 0; t < nt; ++t) {
        // tile t landed (3 own loads); tile t+1 (3 loads) stays in flight
        if (t + 1 < nt) {
            asm volatile("s_waitcnt vmcnt(3)" ::: "memory");
        } else {
            asm volatile("s_waitcnt vmcnt(0)" ::: "memory");
        }
        __builtin_amdgcn_s_barrier();
        __builtin_amdgcn_sched_barrier(0);

        bf16x8 bfr[4], afA[2], afB[2];
        // ---- phase 0: B frags + A frags 0,1; MFMA mi=0,1
        #pragma unroll
        for (int j = 0; j < 4; ++j) {
            const int Rb = wc * 64 + j * 16 + fr;
            bfr[j] = *reinterpret_cast<const bf16x8*>(
                &sb[cur][Rb * 32 + ((lq ^ ((Rb >> 1) & 3)) << 3)]);
        }
        #pragma unroll
        for (int i = 0; i < 2; ++i) {
            const int Ra = wr * 64 + i * 16 + fr;
            afA[i] = *reinterpret_cast<const bf16x8*>(
                &sa[cur][Ra * 32 + ((lq ^ ((Ra >> 1) & 3)) << 3)]);
        }
        __builtin_amdgcn_s_setprio(1);
        #pragma unroll
        for (int mi = 0; mi < 2; ++mi)
            #pragma unroll
            for (int ni = 0; ni < 4; ++ni)
                acc[mi][ni] = __builtin_amdgcn_mfma_f32_16x16x32_bf16(afA[mi], bfr[ni], acc[mi][ni], 0, 0, 0);
        __builtin_amdgcn_s_setprio(0);
        __builtin_amdgcn_s_barrier();
        __builtin_amdgcn_sched_barrier(0);

        // ---- phase 1: A frags 2,3; MFMA mi=2,3
        #pragma unroll
        for (int i = 0; i < 2; ++i) {
            const int Ra = wr * 64 + (2 + i) * 16 + fr;
            afB[i] = *reinterpret_cast<const bf16x8*>(
                &sa[cur][Ra * 32 + ((lq ^ ((Ra >> 1) & 3)) << 3)]);
        }
        __builtin_amdgcn_s_setprio(1);
        #pragma unroll
        for (int mi = 0; mi < 2; ++mi)
            #pragma unroll
            for (int ni = 0; ni < 4; ++ni)
                acc[2 + mi][ni] = __builtin_amdgcn_mfma_f32_16x16x32_bf16(afB[mi], bfr[ni], acc[2 + mi][ni], 0, 0, 0);
        __builtin_amdgcn_s_setprio(0);
        __builtin_amdgcn_s_barrier();       // all reads of buf cur complete past here
        __builtin_amdgcn_sched_barrier(0);

        if (t + 2 < nt) STAGE(t + 2, cur);  // reuse just-freed buffer
        cur ^= 1;
    }

    #pragma unroll
    for (int mi = 0; mi < 4; ++mi) {
        #pragma unroll
        for (int ni = 0; ni < 4; ++ni) {
            const int gc = n0 + wc * 64 + ni * 16 + fr;
            const float bv = bias[gc];
            #pragma unroll
            for (int r = 0; r < 4; ++r) {
                const int gr = m0 + wr * 64 + mi * 16 + lq * 4 + r;
                outp[(size_t)gr * N + gc] = acc[mi][ni][r] + bv;
            }
        }
    }
}

// ---------------------------------------------------------------- sparse attention v6 (round-13 best)
__global__ __launch_bounds__(256) void attn_kernel(
    const unsigned short* __restrict__ qkv, const int* __restrict__ rc,
    unsigned short* __restrict__ attnout)
{
    __shared__ unsigned short Kw[80 * 64];
    __shared__ unsigned short Vt[64 * VTW];
    __shared__ unsigned short Ps[16 * PSW];
    __shared__ float rWs[16][40];
    __shared__ short rCs[16][40];
    __shared__ int   nBs[16];
    __shared__ float qinv[16];

    const int tid = threadIdx.x;
    const int wave = tid >> 6, lane = tid & 63;
    const int lq = lane >> 4, fr = lane & 15;
    const int bid = blockIdx.x;
    const int tb = bid & 127;
    const int h = (bid >> 7) & 7;
    const int b = bid >> 10;
    const int t0 = tb * QB;
    const int base = t0 - 63;

    const unsigned short* kb = qkv + (size_t)b * SEQT * 1536 + 512 + h * 64;
    const unsigned short* vb = qkv + (size_t)b * SEQT * 1536 + 1024 + h * 64;

    for (int c = tid; c < 79 * 8; c += 256) {
        const int r = c >> 3, j = c & 7;
        const int col = base + r;
        u16x8 kv = {0, 0, 0, 0, 0, 0, 0, 0};
        u16x8 vv = {0, 0, 0, 0, 0, 0, 0, 0};
        if (col >= 0) {
            kv = *(const u16x8*)&kb[(size_t)col * 1536 + j * 8];
            vv = *(const u16x8*)&vb[(size_t)col * 1536 + j * 8];
        }
        *(u16x8*)&Kw[r * 64 + ((j ^ (r & 7)) * 8)] = kv;
        #pragma unroll
        for (int e = 0; e < 8; ++e)
            Vt[(j * 8 + e) * VTW + r] = vv[e];
    }
    for (int i = tid; i < 64 * 17; i += 256) {
        const int d = i / 17, s = 79 + (i - d * 17);
        Vt[d * VTW + s] = 0;
    }
    __syncthreads();

    for (int u = 0; u < 4; ++u) {
        const int Q = wave * 4 + u;
        const int t = t0 + Q;
        const int m = b * SEQT + t;

        u16x8 qreg[8];
        #pragma unroll
        for (int j = 0; j < 8; ++j)
            qreg[j] = *(const u16x8*)&qkv[(size_t)m * 1536 + h * 64 + j * 8];

        const int row = Q + lane;
        const int colA = base + row;
        float sA;
        {
            float s = 0.f;
            #pragma unroll
            for (int j = 0; j < 8; ++j) {
                const u16x8 kc = *(const u16x8*)&Kw[row * 64 + ((j ^ (row & 7)) * 8)];
                #pragma unroll
                for (int e = 0; e < 8; ++e)
                    s += bf2f(kc[e]) * bf2f(qreg[j][e]);
            }
            sA = (colA >= NGLOB) ? s * 0.125f : -1e30f;
        }

        int colB = 0;
        bool vB = false;
        if (lane < NGLOB) {
            colB = lane;
            vB = (lane <= t);
        } else if (lane < 32) {
            colB = rc[((size_t)h * SEQT + t) * NRAND + (lane - 16)];
            vB = (colB >= NGLOB) && (colB <= t - WIN);
        }
        #pragma unroll
        for (int j = 0; j < 15; ++j) {
            const int cj = __shfl(colB, 16 + j);
            if (lane >= 16 && lane < 32 && (lane - 16) > j && cj == colB) vB = false;
        }

        float sB = -1e30f;
        if (vB) {
            float s = 0.f;
            const unsigned short* kr = &kb[(size_t)colB * 1536];
            #pragma unroll
            for (int j = 0; j < 8; ++j) {
                const u16x8 kc = *(const u16x8*)&kr[j * 8];
                #pragma unroll
                for (int e = 0; e < 8; ++e)
                    s += bf2f(kc[e]) * bf2f(qreg[j][e]);
            }
            sB = s * 0.125f;
        }

        float mx = fmaxf(sA, sB);
        #pragma unroll
        for (int off = 32; off > 0; off >>= 1) mx = fmaxf(mx, __shfl_xor(mx, off));
        const float e0 = (colA >= NGLOB) ? __expf(sA - mx) : 0.f;
        const float e1 = vB ? __expf(sB - mx) : 0.f;
        float sum = e0 + e1;
        #pragma unroll
        for (int off = 32; off > 0; off >>= 1) sum += __shfl_xor(sum, off);

        Ps[Q * PSW + Q + lane] = f2bf(e0);
        if (lane < 32) Ps[Q * PSW + ((Q + 64 + lane) % 96)] = 0;

        const unsigned long long bm = __ballot(vB);
        const int nB = __popcll(bm);
        const int pos = __popcll(bm & ((1ull << lane) - 1ull));
        if (vB) { rCs[Q][pos] = (short)colB; rWs[Q][pos] = e1; }
        if (lane >= 32 && lane < 36) {
            const int p = nB + (lane - 32);
            rCs[Q][p] = 0; rWs[Q][p] = 0.f;
        }
        if (lane == 0) { nBs[Q] = nB; qinv[Q] = 1.f / sum; }
    }
    __syncthreads();

    const int dmine = wave * 16 + fr;
    f32x4 of = {0.f, 0.f, 0.f, 0.f};
    #pragma unroll
    for (int ks = 0; ks < 3; ++ks) {
        const int s0 = ks * 32 + lq * 8;
        const bf16x8 ap = *reinterpret_cast<const bf16x8*>(&Ps[fr * PSW + s0]);
        const bf16x8 bv = *reinterpret_cast<const bf16x8*>(&Vt[dmine * VTW + s0]);
        of = __builtin_amdgcn_mfma_f32_16x16x32_bf16(ap, bv, of, 0, 0, 0);
    }

    #pragma unroll
    for (int r = 0; r < 4; ++r) {
        const int q2 = lq * 4 + r;
        float acc = of[r];
        const int nb4 = (nBs[q2] + 3) & ~3;
        for (int i = 0; i < nb4; i += 4) {
            const float w0 = rWs[q2][i + 0], w1 = rWs[q2][i + 1];
            const float w2 = rWs[q2][i + 2], w3 = rWs[q2][i + 3];
            const int   c0 = rCs[q2][i + 0], c1 = rCs[q2][i + 1];
            const int   c2 = rCs[q2][i + 2], c3 = rCs[q2][i + 3];
            acc += w0 * bf2f(vb[(size_t)c0 * 1536 + dmine])
                 + w1 * bf2f(vb[(size_t)c1 * 1536 + dmine])
                 + w2 * bf2f(vb[(size_t)c2 * 1536 + dmine])
                 + w3 * bf2f(vb[(size_t)c3 * 1536 + dmine]);
        }
        attnout[(size_t)(b * SEQT + t0 + q2) * CEMB + h * 64 + dmine] = f2bf(acc * qinv[q2]);
    }
}

// ---------------------------------------------------------------- host
extern "C" void kernel_launch(void* const* d_in, const int* in_sizes, int n_in,
                              void* d_out, int out_size, void* d_ws, size_t ws_size,
                              hipStream_t stream)
{
    const float* tok_emb = (const float*)d_in[0];
    const float* pos_emb = (const float*)d_in[1];
    const float* Wq    = (const float*)d_in[2];
    const float* Wk    = (const float*)d_in[3];
    const float* Wv    = (const float*)d_in[4];
    const float* Wproj = (const float*)d_in[5];
    const float* bproj = (const float*)d_in[6];
    const float* ln1g  = (const float*)d_in[7];
    const float* ln1b  = (const float*)d_in[8];
    const float* ln2g  = (const float*)d_in[9];
    const float* ln2b  = (const float*)d_in[10];
    const float* W1    = (const float*)d_in[11];
    const float* b1    = (const float*)d_in[12];
    const float* W2    = (const float*)d_in[13];
    const float* b2    = (const float*)d_in[14];
    const float* lnfg  = (const float*)d_in[15];
    const float* lnfb  = (const float*)d_in[16];
    const float* Wout  = (const float*)d_in[17];
    const float* bout  = (const float*)d_in[18];
    const int*   toks  = (const int*)d_in[19];
    const int*   rcols = (const int*)d_in[20];
    (void)in_sizes; (void)n_in; (void)out_size; (void)ws_size;

    char* ws = (char*)d_ws;
    size_t off = 0;
    auto ALLOC = [&](size_t bytes) -> void* {
        void* p = ws + off;
        off += (bytes + 255) & ~(size_t)255;
        return p;
    };
    float*          x      = (float*)ALLOC((size_t)MROWS * CEMB * 4);
    unsigned short* xnbf   = (unsigned short*)ALLOC((size_t)MROWS * CEMB * 2);
    unsigned short* qkv    = (unsigned short*)ALLOC((size_t)MROWS * 1536 * 2);
    unsigned short* attnbf = (unsigned short*)ALLOC((size_t)MROWS * CEMB * 2);
    unsigned short* hbf    = (unsigned short*)ALLOC((size_t)MROWS * 2048 * 2);
    unsigned short* wqkvT  = (unsigned short*)ALLOC((size_t)NLAYER * 1536 * 512 * 2);
    unsigned short* wprojT = (unsigned short*)ALLOC((size_t)NLAYER * 512 * 512 * 2);
    unsigned short* w1T    = (unsigned short*)ALLOC((size_t)NLAYER * 2048 * 512 * 2);
    unsigned short* w2T    = (unsigned short*)ALLOC((size_t)NLAYER * 512 * 2048 * 2);
    unsigned short* woutT  = (unsigned short*)ALLOC((size_t)VOCAB_N * 512 * 2);

    transpose_all_kernel<<<7072, 256, 0, stream>>>(
        Wq, Wk, Wv, Wproj, W1, W2, Wout, wqkvT, wprojT, w1T, w2T, woutT);

    embed_kernel<<<2048, 256, 0, stream>>>(tok_emb, pos_emb, toks, x);

    for (int l = 0; l < NLAYER; ++l) {
        ln_kernel<<<1024, 256, 0, stream>>>(x, ln1g + l * CEMB, ln1b + l * CEMB, xnbf);
        gemm_kernel<0, 2><<<dim3(24, 32), 256, 0, stream>>>(
            xnbf, wqkvT + (size_t)l * 1536 * 512, nullptr, nullptr, qkv, MROWS, 1536, 512);
        attn_kernel<<<2048, 256, 0, stream>>>(qkv, rcols + (size_t)l * NHEAD * SEQT * NRAND, attnbf);
        gemm_kernel<1, 2><<<dim3(8, 32), 256, 0, stream>>>(
            attnbf, wprojT + (size_t)l * 512 * 512, bproj + l * CEMB, x, x, MROWS, 512, 512);
        ln_kernel<<<1024, 256, 0, stream>>>(x, ln2g + l * CEMB, ln2b + l * CEMB, xnbf);
        gemm_kernel<2, 4><<<dim3(16, 32), 256, 0, stream>>>(
            xnbf, w1T + (size_t)l * 2048 * 512, b1 + l * 2048, nullptr, hbf, MROWS, 2048, 512);
        gemm_kernel<1, 2><<<dim3(8, 32), 256, 0, stream>>>(
            hbf, w2T + (size_t)l * 512 * 2048, b2 + l * CEMB, x, x, MROWS, 512, 2048);
    }
    ln_kernel<<<1024, 256, 0, stream>>>(x, lnfg, lnfb, xnbf);
    gemm_logits_kernel<<<dim3(125, 32), 512, 0, stream>>>(
        xnbf, woutT, bout, (float*)d_out, MROWS, VOCAB_N, 512);
}

// Round 16
// 1012.316 us; speedup vs baseline: 1.0104x; 1.0104x over previous
//
#include <hip/hip_runtime.h>
#include <hip/hip_bf16.h>

#define NLAYER 4
#define NHEAD 8
#define CEMB 512
#define HS 64
#define VOCAB_N 32000
#define SEQT 2048
#define BATCH_N 2
#define MROWS (BATCH_N * SEQT)   /* 4096 */
#define WIN 64
#define NGLOB 16
#define NRAND 16
#define QB 16
#define VTW 104
#define PSW 104

typedef __attribute__((ext_vector_type(8))) __bf16 bf16x8;
typedef __attribute__((ext_vector_type(4))) float f32x4;
typedef __attribute__((ext_vector_type(8))) unsigned short u16x8;

__device__ __forceinline__ unsigned short f2bf(float f) {
    unsigned u = __float_as_uint(f);
    u += 0x7fffu + ((u >> 16) & 1u);      // RNE
    return (unsigned short)(u >> 16);
}
__device__ __forceinline__ float bf2f(unsigned short v) {
    return __uint_as_float((unsigned)v << 16);
}

// async global->LDS, 16B per lane
__device__ __forceinline__ void stage16(const unsigned short* g, unsigned short* l) {
    __builtin_amdgcn_global_load_lds(
        (const __attribute__((address_space(1))) void*)g,
        (__attribute__((address_space(3))) void*)l, 16, 0, 0);
}

// ---------------------------------------------------------------- unified weight transpose
__global__ __launch_bounds__(256) void transpose_all_kernel(
    const float* __restrict__ Wq, const float* __restrict__ Wk,
    const float* __restrict__ Wv, const float* __restrict__ Wproj,
    const float* __restrict__ W1, const float* __restrict__ W2,
    const float* __restrict__ Wout,
    unsigned short* __restrict__ wqkvT, unsigned short* __restrict__ wprojT,
    unsigned short* __restrict__ w1T, unsigned short* __restrict__ w2T,
    unsigned short* __restrict__ woutT)
{
    __shared__ float tle[64][65];
    const int bid = blockIdx.x;
    const float* src; unsigned short* dst; int Ks, Ns, k0, n0;
    if (bid < 768) {
        const int tile = bid & 7, rest = bid >> 3;
        const int l = rest / 24, r2 = rest % 24;
        const int sel = r2 >> 3, h = r2 & 7;
        const float* W = (sel == 0) ? Wq : (sel == 1) ? Wk : Wv;
        src = W + (size_t)(l * 8 + h) * 512 * 64;
        dst = wqkvT + ((size_t)l * 1536 + sel * 512 + h * 64) * 512;
        Ks = 512; Ns = 64; k0 = tile * 64; n0 = 0;
    } else if (bid < 1024) {
        const int idx = bid - 768, l = idx >> 6, t6 = idx & 63;
        src = Wproj + (size_t)l * 512 * 512;
        dst = wprojT + (size_t)l * 512 * 512;
        Ks = 512; Ns = 512; k0 = (t6 >> 3) * 64; n0 = (t6 & 7) * 64;
    } else if (bid < 2048) {
        const int idx = bid - 1024, l = idx >> 8, t8 = idx & 255;
        src = W1 + (size_t)l * 512 * 2048;
        dst = w1T + (size_t)l * 2048 * 512;
        Ks = 512; Ns = 2048; k0 = (t8 >> 5) * 64; n0 = (t8 & 31) * 64;
    } else if (bid < 3072) {
        const int idx = bid - 2048, l = idx >> 8, t8 = idx & 255;
        src = W2 + (size_t)l * 2048 * 512;
        dst = w2T + (size_t)l * 512 * 2048;
        Ks = 2048; Ns = 512; k0 = (t8 >> 3) * 64; n0 = (t8 & 7) * 64;
    } else {
        const int idx = bid - 3072;
        src = Wout; dst = woutT;
        Ks = 512; Ns = 32000; k0 = (idx / 500) * 64; n0 = (idx % 500) * 64;
    }
    const int tid = threadIdx.x;
    #pragma unroll
    for (int i = 0; i < 16; ++i) {
        const int idx = tid + i * 256;
        const int r = idx >> 6, c = idx & 63;
        tle[r][c] = src[(size_t)(k0 + r) * Ns + n0 + c];
    }
    __syncthreads();
    #pragma unroll
    for (int i = 0; i < 16; ++i) {
        const int idx = tid + i * 256;
        const int c = idx >> 6, r = idx & 63;
        dst[(size_t)(n0 + c) * Ks + k0 + r] = f2bf(tle[r][c]);
    }
}

// ---------------------------------------------------------------- embedding
__global__ __launch_bounds__(256) void embed_kernel(
    const float* __restrict__ tok_emb, const float* __restrict__ pos_emb,
    const int* __restrict__ toks, float* __restrict__ x)
{
    int i = blockIdx.x * 256 + threadIdx.x;
    int m = i >> 7;
    int c = (i & 127) << 2;
    int tok = toks[m];
    const float4 a = *(const float4*)&tok_emb[(size_t)tok * CEMB + c];
    const float4 p = *(const float4*)&pos_emb[(size_t)(m & (SEQT - 1)) * CEMB + c];
    float4 o;
    o.x = a.x + p.x; o.y = a.y + p.y; o.z = a.z + p.z; o.w = a.w + p.w;
    *(float4*)&x[(size_t)m * CEMB + c] = o;
}

// ---------------------------------------------------------------- layernorm
__global__ __launch_bounds__(256) void ln_kernel(
    const float* __restrict__ x, const float* __restrict__ g,
    const float* __restrict__ b, unsigned short* __restrict__ out)
{
    const int wave = threadIdx.x >> 6, lane = threadIdx.x & 63;
    const int m = blockIdx.x * 4 + wave;
    const float* row = x + (size_t)m * CEMB;
    const float4 v0 = *(const float4*)&row[lane * 8];
    const float4 v1 = *(const float4*)&row[lane * 8 + 4];
    float s  = v0.x + v0.y + v0.z + v0.w + v1.x + v1.y + v1.z + v1.w;
    float s2 = v0.x*v0.x + v0.y*v0.y + v0.z*v0.z + v0.w*v0.w
             + v1.x*v1.x + v1.y*v1.y + v1.z*v1.z + v1.w*v1.w;
    #pragma unroll
    for (int off = 32; off > 0; off >>= 1) {
        s  += __shfl_xor(s, off);
        s2 += __shfl_xor(s2, off);
    }
    const float mu  = s * (1.f / CEMB);
    const float var = s2 * (1.f / CEMB) - mu * mu;
    const float rs  = rsqrtf(var + 1e-5f);
    const float vals[8] = {v0.x, v0.y, v0.z, v0.w, v1.x, v1.y, v1.z, v1.w};
    u16x8 o;
    #pragma unroll
    for (int j = 0; j < 8; ++j)
        o[j] = f2bf((vals[j] - mu) * rs * g[lane * 8 + j] + b[lane * 8 + j]);
    *(u16x8*)&out[(size_t)m * CEMB + lane * 8] = o;
}

// ---------------------------------------------------------------- MFMA GEMM (r8 triple-buffer counted vmcnt + T2 swizzle)
// MODE 0: bf16 out, no bias | 1: f32 out +bias +resid | 2: bf16 out +bias relu
template<int MODE, int NF>
__global__ __launch_bounds__(256) void gemm_kernel(
    const unsigned short* __restrict__ A, const unsigned short* __restrict__ Bt,
    const float* __restrict__ bias, const float* resid, void* outp,
    int M, int N, int K)
{
    __shared__ unsigned short sa[3][128 * 32];
    __shared__ unsigned short sb[3][NF * 32 * 32];
    const int tid = threadIdx.x;
    const int lane = tid & 63;
    const int wave = tid >> 6;
    const int wr = wave >> 1, wc = wave & 1;
    const int m0 = blockIdx.y * 128;
    const int n0 = blockIdx.x * (NF * 32);

    const int c0a = (wave * 2) * 64 + lane;
    const int c1a = (wave * 2 + 1) * 64 + lane;
    const int r0 = c0a >> 2, kk0 = (((c0a & 3) ^ ((r0 >> 1) & 3)) * 8);
    const int r1 = c1a >> 2, kk1 = (((c1a & 3) ^ ((r1 >> 1) & 3)) * 8);
    const unsigned short* ga0 = A + (size_t)(m0 + r0) * K + kk0;
    const unsigned short* ga1 = A + (size_t)(m0 + r1) * K + kk1;
    const int o0 = (wave * 2) * 512;
    const int o1 = (wave * 2 + 1) * 512;
    const int cb0 = (NF == 4) ? c0a : wave * 64 + lane;
    const int cb1 = c1a;
    const int rb0 = cb0 >> 2, kb0 = (((cb0 & 3) ^ ((rb0 >> 1) & 3)) * 8);
    const int rb1 = cb1 >> 2, kb1 = (((cb1 & 3) ^ ((rb1 >> 1) & 3)) * 8);
    const unsigned short* gb0 = Bt + (size_t)(n0 + rb0) * K + kb0;
    const unsigned short* gb1 = Bt + (size_t)(n0 + rb1) * K + kb1;
    const int ob0 = (NF == 4) ? o0 : wave * 512;
    const int ob1 = o1;

    f32x4 acc[4][NF] = {};
    const int lq = lane >> 4;
    const int fr = lane & 15;

    auto STAGE = [&](int tile, int buf) {
        const int kk = tile << 5;
        stage16(ga0 + kk, &sa[buf][o0]);
        stage16(ga1 + kk, &sa[buf][o1]);
        stage16(gb0 + kk, &sb[buf][ob0]);
        if constexpr (NF == 4) stage16(gb1 + kk, &sb[buf][ob1]);
    };

    const int nt = K >> 5;
    STAGE(0, 0);
    STAGE(1, 1);

    int cur = 0;
    for (int t = 0; t < nt; ++t) {
        if (t + 1 < nt) {
            if constexpr (NF == 2) asm volatile("s_waitcnt vmcnt(3)" ::: "memory");
            else                   asm volatile("s_waitcnt vmcnt(4)" ::: "memory");
        } else {
            asm volatile("s_waitcnt vmcnt(0)" ::: "memory");
        }
        __builtin_amdgcn_s_barrier();
        __builtin_amdgcn_sched_barrier(0);

        if (t + 2 < nt) {
            int b2 = cur + 2; if (b2 >= 3) b2 -= 3;
            STAGE(t + 2, b2);
        }

        bf16x8 af[4], bfr[NF];
        #pragma unroll
        for (int i = 0; i < 4; ++i) {
            const int Ra = wr * 64 + i * 16 + fr;
            af[i] = *reinterpret_cast<const bf16x8*>(
                &sa[cur][Ra * 32 + (((lq ^ ((Ra >> 1) & 3))) << 3)]);
        }
        #pragma unroll
        for (int i = 0; i < NF; ++i) {
            const int Rb = wc * (NF * 16) + i * 16 + fr;
            bfr[i] = *reinterpret_cast<const bf16x8*>(
                &sb[cur][Rb * 32 + (((lq ^ ((Rb >> 1) & 3))) << 3)]);
        }
        #pragma unroll
        for (int mi = 0; mi < 4; ++mi)
            #pragma unroll
            for (int ni = 0; ni < NF; ++ni)
                acc[mi][ni] = __builtin_amdgcn_mfma_f32_16x16x32_bf16(af[mi], bfr[ni], acc[mi][ni], 0, 0, 0);

        cur = (cur == 2) ? 0 : cur + 1;
    }

    #pragma unroll
    for (int mi = 0; mi < 4; ++mi) {
        #pragma unroll
        for (int ni = 0; ni < NF; ++ni) {
            const int gc = n0 + wc * (NF * 16) + ni * 16 + fr;
            const float bv = (MODE != 0) ? bias[gc] : 0.f;
            #pragma unroll
            for (int r = 0; r < 4; ++r) {
                const int gr = m0 + wr * 64 + mi * 16 + lq * 4 + r;
                float v = acc[mi][ni][r] + bv;
                if (MODE == 1) v += resid[(size_t)gr * N + gc];
                if (MODE == 2) v = fmaxf(v, 0.f);
                if (MODE == 0 || MODE == 2) {
                    ((unsigned short*)outp)[(size_t)gr * N + gc] = f2bf(v);
                } else {
                    ((float*)outp)[(size_t)gr * N + gc] = v;
                }
            }
        }
    }
}

// ---------------------------------------------------------------- logits GEMM: 256x128 tile, 512 threads (r13 best)
__global__ __launch_bounds__(512) void gemm_logits_kernel(
    const unsigned short* __restrict__ A, const unsigned short* __restrict__ Bt,
    const float* __restrict__ bias, float* __restrict__ outp,
    int M, int N, int K)
{
    __shared__ unsigned short sa[2][256 * 32];   // 16 KB each
    __shared__ unsigned short sb[2][128 * 32];   // 8 KB each
    const int tid = threadIdx.x;
    const int lane = tid & 63;
    const int wave = tid >> 6;
    const int wr = wave >> 1, wc = wave & 1;

    const int flat = blockIdx.y * gridDim.x + blockIdx.x;   // 0..3999
    const int q = (gridDim.x * gridDim.y) >> 3;             // 500
    const int nl = (flat & 7) * q + (flat >> 3);
    const int by = nl & 15;          // M-block (16)
    const int bx = nl >> 4;          // N-block (250)
    const int m0 = by * 256;
    const int n0 = bx * 128;

    const int c0a = (wave * 2) * 64 + lane;
    const int c1a = (wave * 2 + 1) * 64 + lane;
    const int r0 = c0a >> 2, kk0 = (((c0a & 3) ^ ((r0 >> 1) & 3)) * 8);
    const int r1 = c1a >> 2, kk1 = (((c1a & 3) ^ ((r1 >> 1) & 3)) * 8);
    const unsigned short* ga0 = A + (size_t)(m0 + r0) * K + kk0;
    const unsigned short* ga1 = A + (size_t)(m0 + r1) * K + kk1;
    const int o0 = (wave * 2) * 512;
    const int o1 = (wave * 2 + 1) * 512;
    const int cb0 = wave * 64 + lane;
    const int rb0 = cb0 >> 2, kb0 = (((cb0 & 3) ^ ((rb0 >> 1) & 3)) * 8);
    const unsigned short* gb0 = Bt + (size_t)(n0 + rb0) * K + kb0;
    const int ob0 = wave * 512;

    f32x4 acc[4][4] = {};
    const int lq = lane >> 4;
    const int fr = lane & 15;

    auto STAGE = [&](int t, int buf) {
        const int kk = t << 5;
        stage16(ga0 + kk, &sa[buf][o0]);
        stage16(ga1 + kk, &sa[buf][o1]);
        stage16(gb0 + kk, &sb[buf][ob0]);
    };

    const int nt = K >> 5;
    STAGE(0, 0);
    __syncthreads();
    int cur = 0;
    for (int t = 0; t < nt; ++t) {
        if (t + 1 < nt) STAGE(t + 1, cur ^ 1);
        bf16x8 af[4], bfr[4];
        #pragma unroll
        for (int i = 0; i < 4; ++i) {
            const int Ra = wr * 64 + i * 16 + fr;
            af[i] = *reinterpret_cast<const bf16x8*>(
                &sa[cur][Ra * 32 + (((lq ^ ((Ra >> 1) & 3))) << 3)]);
        }
        #pragma unroll
        for (int i = 0; i < 4; ++i) {
            const int Rb = wc * 64 + i * 16 + fr;
            bfr[i] = *reinterpret_cast<const bf16x8*>(
                &sb[cur][Rb * 32 + (((lq ^ ((Rb >> 1) & 3))) << 3)]);
        }
        #pragma unroll
        for (int mi = 0; mi < 4; ++mi)
            #pragma unroll
            for (int ni = 0; ni < 4; ++ni)
                acc[mi][ni] = __builtin_amdgcn_mfma_f32_16x16x32_bf16(af[mi], bfr[ni], acc[mi][ni], 0, 0, 0);
        __syncthreads();
        cur ^= 1;
    }

    #pragma unroll
    for (int mi = 0; mi < 4; ++mi) {
        #pragma unroll
        for (int ni = 0; ni < 4; ++ni) {
            const int gc = n0 + wc * 64 + ni * 16 + fr;
            const float bv = bias[gc];
            #pragma unroll
            for (int r = 0; r < 4; ++r) {
                const int gr = m0 + wr * 64 + mi * 16 + lq * 4 + r;
                outp[(size_t)gr * N + gc] = acc[mi][ni][r] + bv;
            }
        }
    }
}

// ---------------------------------------------------------------- sparse attention v6 (round-13 best)
__global__ __launch_bounds__(256) void attn_kernel(
    const unsigned short* __restrict__ qkv, const int* __restrict__ rc,
    unsigned short* __restrict__ attnout)
{
    __shared__ unsigned short Kw[80 * 64];
    __shared__ unsigned short Vt[64 * VTW];
    __shared__ unsigned short Ps[16 * PSW];
    __shared__ float rWs[16][40];
    __shared__ short rCs[16][40];
    __shared__ int   nBs[16];
    __shared__ float qinv[16];

    const int tid = threadIdx.x;
    const int wave = tid >> 6, lane = tid & 63;
    const int lq = lane >> 4, fr = lane & 15;
    const int bid = blockIdx.x;
    const int tb = bid & 127;
    const int h = (bid >> 7) & 7;
    const int b = bid >> 10;
    const int t0 = tb * QB;
    const int base = t0 - 63;

    const unsigned short* kb = qkv + (size_t)b * SEQT * 1536 + 512 + h * 64;
    const unsigned short* vb = qkv + (size_t)b * SEQT * 1536 + 1024 + h * 64;

    for (int c = tid; c < 79 * 8; c += 256) {
        const int r = c >> 3, j = c & 7;
        const int col = base + r;
        u16x8 kv = {0, 0, 0, 0, 0, 0, 0, 0};
        u16x8 vv = {0, 0, 0, 0, 0, 0, 0, 0};
        if (col >= 0) {
            kv = *(const u16x8*)&kb[(size_t)col * 1536 + j * 8];
            vv = *(const u16x8*)&vb[(size_t)col * 1536 + j * 8];
        }
        *(u16x8*)&Kw[r * 64 + ((j ^ (r & 7)) * 8)] = kv;
        #pragma unroll
        for (int e = 0; e < 8; ++e)
            Vt[(j * 8 + e) * VTW + r] = vv[e];
    }
    for (int i = tid; i < 64 * 17; i += 256) {
        const int d = i / 17, s = 79 + (i - d * 17);
        Vt[d * VTW + s] = 0;
    }
    __syncthreads();

    for (int u = 0; u < 4; ++u) {
        const int Q = wave * 4 + u;
        const int t = t0 + Q;
        const int m = b * SEQT + t;

        u16x8 qreg[8];
        #pragma unroll
        for (int j = 0; j < 8; ++j)
            qreg[j] = *(const u16x8*)&qkv[(size_t)m * 1536 + h * 64 + j * 8];

        const int row = Q + lane;
        const int colA = base + row;
        float sA;
        {
            float s = 0.f;
            #pragma unroll
            for (int j = 0; j < 8; ++j) {
                const u16x8 kc = *(const u16x8*)&Kw[row * 64 + ((j ^ (row & 7)) * 8)];
                #pragma unroll
                for (int e = 0; e < 8; ++e)
                    s += bf2f(kc[e]) * bf2f(qreg[j][e]);
            }
            sA = (colA >= NGLOB) ? s * 0.125f : -1e30f;
        }

        int colB = 0;
        bool vB = false;
        if (lane < NGLOB) {
            colB = lane;
            vB = (lane <= t);
        } else if (lane < 32) {
            colB = rc[((size_t)h * SEQT + t) * NRAND + (lane - 16)];
            vB = (colB >= NGLOB) && (colB <= t - WIN);
        }
        #pragma unroll
        for (int j = 0; j < 15; ++j) {
            const int cj = __shfl(colB, 16 + j);
            if (lane >= 16 && lane < 32 && (lane - 16) > j && cj == colB) vB = false;
        }

        float sB = -1e30f;
        if (vB) {
            float s = 0.f;
            const unsigned short* kr = &kb[(size_t)colB * 1536];
            #pragma unroll
            for (int j = 0; j < 8; ++j) {
                const u16x8 kc = *(const u16x8*)&kr[j * 8];
                #pragma unroll
                for (int e = 0; e < 8; ++e)
                    s += bf2f(kc[e]) * bf2f(qreg[j][e]);
            }
            sB = s * 0.125f;
        }

        float mx = fmaxf(sA, sB);
        #pragma unroll
        for (int off = 32; off > 0; off >>= 1) mx = fmaxf(mx, __shfl_xor(mx, off));
        const float e0 = (colA >= NGLOB) ? __expf(sA - mx) : 0.f;
        const float e1 = vB ? __expf(sB - mx) : 0.f;
        float sum = e0 + e1;
        #pragma unroll
        for (int off = 32; off > 0; off >>= 1) sum += __shfl_xor(sum, off);

        Ps[Q * PSW + Q + lane] = f2bf(e0);
        if (lane < 32) Ps[Q * PSW + ((Q + 64 + lane) % 96)] = 0;

        const unsigned long long bm = __ballot(vB);
        const int nB = __popcll(bm);
        const int pos = __popcll(bm & ((1ull << lane) - 1ull));
        if (vB) { rCs[Q][pos] = (short)colB; rWs[Q][pos] = e1; }
        if (lane >= 32 && lane < 36) {
            const int p = nB + (lane - 32);
            rCs[Q][p] = 0; rWs[Q][p] = 0.f;
        }
        if (lane == 0) { nBs[Q] = nB; qinv[Q] = 1.f / sum; }
    }
    __syncthreads();

    const int dmine = wave * 16 + fr;
    f32x4 of = {0.f, 0.f, 0.f, 0.f};
    #pragma unroll
    for (int ks = 0; ks < 3; ++ks) {
        const int s0 = ks * 32 + lq * 8;
        const bf16x8 ap = *reinterpret_cast<const bf16x8*>(&Ps[fr * PSW + s0]);
        const bf16x8 bv = *reinterpret_cast<const bf16x8*>(&Vt[dmine * VTW + s0]);
        of = __builtin_amdgcn_mfma_f32_16x16x32_bf16(ap, bv, of, 0, 0, 0);
    }

    #pragma unroll
    for (int r = 0; r < 4; ++r) {
        const int q2 = lq * 4 + r;
        float acc = of[r];
        const int nb4 = (nBs[q2] + 3) & ~3;
        for (int i = 0; i < nb4; i += 4) {
            const float w0 = rWs[q2][i + 0], w1 = rWs[q2][i + 1];
            const float w2 = rWs[q2][i + 2], w3 = rWs[q2][i + 3];
            const int   c0 = rCs[q2][i + 0], c1 = rCs[q2][i + 1];
            const int   c2 = rCs[q2][i + 2], c3 = rCs[q2][i + 3];
            acc += w0 * bf2f(vb[(size_t)c0 * 1536 + dmine])
                 + w1 * bf2f(vb[(size_t)c1 * 1536 + dmine])
                 + w2 * bf2f(vb[(size_t)c2 * 1536 + dmine])
                 + w3 * bf2f(vb[(size_t)c3 * 1536 + dmine]);
        }
        attnout[(size_t)(b * SEQT + t0 + q2) * CEMB + h * 64 + dmine] = f2bf(acc * qinv[q2]);
    }
}

// ---------------------------------------------------------------- host
extern "C" void kernel_launch(void* const* d_in, const int* in_sizes, int n_in,
                              void* d_out, int out_size, void* d_ws, size_t ws_size,
                              hipStream_t stream)
{
    const float* tok_emb = (const float*)d_in[0];
    const float* pos_emb = (const float*)d_in[1];
    const float* Wq    = (const float*)d_in[2];
    const float* Wk    = (const float*)d_in[3];
    const float* Wv    = (const float*)d_in[4];
    const float* Wproj = (const float*)d_in[5];
    const float* bproj = (const float*)d_in[6];
    const float* ln1g  = (const float*)d_in[7];
    const float* ln1b  = (const float*)d_in[8];
    const float* ln2g  = (const float*)d_in[9];
    const float* ln2b  = (const float*)d_in[10];
    const float* W1    = (const float*)d_in[11];
    const float* b1    = (const float*)d_in[12];
    const float* W2    = (const float*)d_in[13];
    const float* b2    = (const float*)d_in[14];
    const float* lnfg  = (const float*)d_in[15];
    const float* lnfb  = (const float*)d_in[16];
    const float* Wout  = (const float*)d_in[17];
    const float* bout  = (const float*)d_in[18];
    const int*   toks  = (const int*)d_in[19];
    const int*   rcols = (const int*)d_in[20];
    (void)in_sizes; (void)n_in; (void)out_size; (void)ws_size;

    char* ws = (char*)d_ws;
    size_t off = 0;
    auto ALLOC = [&](size_t bytes) -> void* {
        void* p = ws + off;
        off += (bytes + 255) & ~(size_t)255;
        return p;
    };
    float*          x      = (float*)ALLOC((size_t)MROWS * CEMB * 4);
    unsigned short* xnbf   = (unsigned short*)ALLOC((size_t)MROWS * CEMB * 2);
    unsigned short* qkv    = (unsigned short*)ALLOC((size_t)MROWS * 1536 * 2);
    unsigned short* attnbf = (unsigned short*)ALLOC((size_t)MROWS * CEMB * 2);
    unsigned short* hbf    = (unsigned short*)ALLOC((size_t)MROWS * 2048 * 2);
    unsigned short* wqkvT  = (unsigned short*)ALLOC((size_t)NLAYER * 1536 * 512 * 2);
    unsigned short* wprojT = (unsigned short*)ALLOC((size_t)NLAYER * 512 * 512 * 2);
    unsigned short* w1T    = (unsigned short*)ALLOC((size_t)NLAYER * 2048 * 512 * 2);
    unsigned short* w2T    = (unsigned short*)ALLOC((size_t)NLAYER * 512 * 2048 * 2);
    unsigned short* woutT  = (unsigned short*)ALLOC((size_t)VOCAB_N * 512 * 2);

    transpose_all_kernel<<<7072, 256, 0, stream>>>(
        Wq, Wk, Wv, Wproj, W1, W2, Wout, wqkvT, wprojT, w1T, w2T, woutT);

    embed_kernel<<<2048, 256, 0, stream>>>(tok_emb, pos_emb, toks, x);

    for (int l = 0; l < NLAYER; ++l) {
        ln_kernel<<<1024, 256, 0, stream>>>(x, ln1g + l * CEMB, ln1b + l * CEMB, xnbf);
        gemm_kernel<0, 2><<<dim3(24, 32), 256, 0, stream>>>(
            xnbf, wqkvT + (size_t)l * 1536 * 512, nullptr, nullptr, qkv, MROWS, 1536, 512);
        attn_kernel<<<2048, 256, 0, stream>>>(qkv, rcols + (size_t)l * NHEAD * SEQT * NRAND, attnbf);
        gemm_kernel<1, 2><<<dim3(8, 32), 256, 0, stream>>>(
            attnbf, wprojT + (size_t)l * 512 * 512, bproj + l * CEMB, x, x, MROWS, 512, 512);
        ln_kernel<<<1024, 256, 0, stream>>>(x, ln2g + l * CEMB, ln2b + l * CEMB, xnbf);
        gemm_kernel<2, 4><<<dim3(16, 32), 256, 0, stream>>>(
            xnbf, w1T + (size_t)l * 2048 * 512, b1 + l * 2048, nullptr, hbf, MROWS, 2048, 512);
        gemm_kernel<1, 2><<<dim3(8, 32), 256, 0, stream>>>(
            hbf, w2T + (size_t)l * 512 * 2048, b2 + l * CEMB, x, x, MROWS, 512, 2048);
    }
    ln_kernel<<<1024, 256, 0, stream>>>(x, lnfg, lnfb, xnbf);
    gemm_logits_kernel<<<dim3(250, 16), 512, 0, stream>>>(
        xnbf, woutT, bout, (float*)d_out, MROWS, VOCAB_N, 512);
}